// Round 1
// baseline (298.842 us; speedup 1.0000x reference)
//
#include <hip/hip_runtime.h>

// PadWithin: out[b,c,2i,2j] = feats[b,c,i,j], all other entries zero.
// feats: (16,64,128,128) fp32 -> out: (16,64,256,256) fp32.
// Pure memory-movement. One thread per output float4 (16 B/lane stores).
// Even output rows: read input float2 (cols 2k,2k+1), store (x,0,y,0).
// Odd output rows: store zeros (required: d_out is poisoned to 0xAA each call).

#define IN_H 128
#define IN_W 128
#define OUT_H 256
#define OUT_W 256

__global__ __launch_bounds__(256) void pad_within_kernel(
    const float* __restrict__ in, float* __restrict__ out) {
    // v indexes output float4s: total = 16*64*256*256/4 = 16,777,216
    unsigned v = blockIdx.x * blockDim.x + threadIdx.x;

    unsigned col4 = v & 63u;   // float4 index within output row (64 per row)
    unsigned row  = v >> 6;    // global output row, 0..262143
    unsigned oh   = row & 255u;
    unsigned bc   = row >> 8;  // b*C + c

    float4 val;
    if (oh & 1u) {
        val = make_float4(0.f, 0.f, 0.f, 0.f);
    } else {
        // input row bc*128 + oh/2; float2 at col4 covers input cols 2*col4, 2*col4+1
        const float2* irow =
            (const float2*)(in + ((size_t)bc * IN_H + (oh >> 1)) * IN_W);
        float2 x = irow[col4];
        val = make_float4(x.x, 0.f, x.y, 0.f);
    }
    ((float4*)out)[v] = val;
}

extern "C" void kernel_launch(void* const* d_in, const int* in_sizes, int n_in,
                              void* d_out, int out_size, void* d_ws, size_t ws_size,
                              hipStream_t stream) {
    const float* feats = (const float*)d_in[0];
    float* out = (float*)d_out;
    // out_size = 16*64*256*256 = 67,108,864 floats -> 16,777,216 float4s
    unsigned n_vec4 = (unsigned)(out_size / 4);
    dim3 block(256);
    dim3 grid(n_vec4 / 256);
    pad_within_kernel<<<grid, block, 0, stream>>>(feats, out);
}